// Round 6
// baseline (488.895 us; speedup 1.0000x reference)
//
#include <hip/hip_runtime.h>
#include <hip/hip_bf16.h>

typedef __bf16 bf16_t;
typedef bf16_t bf16x8 __attribute__((ext_vector_type(8)));
typedef float floatx4 __attribute__((ext_vector_type(4)));

#define BB 4
#define NN 4096
#define QDIM 1024
#define HEADS 8
#define DHEAD 64
#define HID 512
#define ROWS (BB*NN)      /* 16384 */
#define QKV_LD 1536

__device__ __forceinline__ float b2f(bf16_t v){ return (float)v; }
__device__ __forceinline__ bf16_t f2b(float v){ return (bf16_t)v; }

__device__ __forceinline__ bf16x8 load8(const bf16_t* p) { return *(const bf16x8*)p; }
__device__ __forceinline__ bf16x8 load8(const float* p) {
  float4 a = *(const float4*)p;
  float4 b = *(const float4*)(p + 4);
  bf16x8 r;
  r[0]=f2b(a.x); r[1]=f2b(a.y); r[2]=f2b(a.z); r[3]=f2b(a.w);
  r[4]=f2b(b.x); r[5]=f2b(b.y); r[6]=f2b(b.z); r[7]=f2b(b.w);
  return r;
}
__device__ __forceinline__ void store_out(bf16_t* p, float v){ *p = f2b(v); }
__device__ __forceinline__ void store_out(float*  p, float v){ *p = v; }

// ---------------- workspace layout (bytes); total ~71.5MB (<114.6MB proven) -
static constexpr size_t OFF_QKV = 0;                      // 16384*1536*2 = 50331648
static constexpr size_t OFF_WT  = 50331648;               // 1536*1024*2  = 3145728
static constexpr size_t OFF_WOT = OFF_WT  + 3145728;      // 1024*512*2   = 1048576
static constexpr size_t OFF_SP  = OFF_WOT + 1048576;      // 4*32*512*8   = 1048576
static constexpr size_t OFF_SF  = OFF_SP  + 1048576;      // 4*512*8      = 16384
static constexpr size_t OFF_CP  = OFF_SF  + 16384;        // 4*32*4096*4  = 2097152
static constexpr size_t OFF_CTX = OFF_CP  + 2097152;      // 32*4096*4    = 524288
static constexpr size_t OFF_ATT = OFF_CTX + 524288;       // 16384*512*2  = 16777216

// ---------------- 64x64 tile transpose: float in -> bf16 out ---------------
__global__ __launch_bounds__(256) void transpose_tile(
    const float* __restrict__ in, bf16_t* __restrict__ out, int R, int C) {
  __shared__ bf16_t T[64][68];
  int r0 = blockIdx.y * 64, c0 = blockIdx.x * 64;
  int t = threadIdx.x;
#pragma unroll
  for (int i = 0; i < 2; ++i) {
    int u = t + i * 256; int rr = u >> 3, c8 = (u & 7) * 8;
    bf16x8 v = load8(&in[(size_t)(r0 + rr) * C + c0 + c8]);
#pragma unroll
    for (int j = 0; j < 8; ++j) T[c8 + j][rr] = v[j];
  }
  __syncthreads();
#pragma unroll
  for (int i = 0; i < 2; ++i) {
    int u = t + i * 256; int cr = u >> 3, r8 = (u & 7) * 8;
    bf16x8 v;
#pragma unroll
    for (int j = 0; j < 8; ++j) v[j] = T[cr][r8 + j];
    *(bf16x8*)&out[(size_t)(c0 + cr) * R + r0 + r8] = v;
  }
}

// ------- 128x128 MFMA GEMM: C[M,N] = A[M,K] @ BT[N,K]^T (+optional bias) ---
// m89-verified C/D layout: row=(lane>>4)*4+reg, col=lane&15.
template <typename AT, typename OT>
__global__ __launch_bounds__(256, 2) void gemm128(
    const AT* __restrict__ A, int lda,
    const bf16_t* __restrict__ BT, int ldb,
    OT* __restrict__ C, int ldc,
    const float* __restrict__ bias, int K) {
  __shared__ bf16_t As[128][56];
  __shared__ bf16_t Bs[128][56];
  int m0 = blockIdx.y * 128, n0 = blockIdx.x * 128;
  int t = threadIdx.x;
  int w = t >> 6, lane = t & 63;
  int wm = (w >> 1) * 64, wn = (w & 1) * 64;
  int lr = lane & 15, lk = (lane >> 4) * 8;

  floatx4 acc[4][4];
#pragma unroll
  for (int mi = 0; mi < 4; ++mi)
#pragma unroll
    for (int ni = 0; ni < 4; ++ni) acc[mi][ni] = (floatx4){0.f, 0.f, 0.f, 0.f};

  for (int k0 = 0; k0 < K; k0 += 32) {
#pragma unroll
    for (int i = 0; i < 2; ++i) {
      int u = t + i * 256; int r = u >> 2, c = (u & 3) * 8;
      *(bf16x8*)&As[r][c] = load8(&A[(size_t)(m0 + r) * lda + k0 + c]);
      *(bf16x8*)&Bs[r][c] = load8(&BT[(size_t)(n0 + r) * ldb + k0 + c]);
    }
    __syncthreads();
    bf16x8 af[4], bfr[4];
#pragma unroll
    for (int mi = 0; mi < 4; ++mi) af[mi] = *(const bf16x8*)&As[wm + mi * 16 + lr][lk];
#pragma unroll
    for (int ni = 0; ni < 4; ++ni) bfr[ni] = *(const bf16x8*)&Bs[wn + ni * 16 + lr][lk];
#pragma unroll
    for (int mi = 0; mi < 4; ++mi)
#pragma unroll
      for (int ni = 0; ni < 4; ++ni)
        acc[mi][ni] = __builtin_amdgcn_mfma_f32_16x16x32_bf16(af[mi], bfr[ni], acc[mi][ni], 0, 0, 0);
    __syncthreads();
  }
  int quad = (lane >> 4);
#pragma unroll
  for (int ni = 0; ni < 4; ++ni) {
    int gc = n0 + wn + ni * 16 + lr;
    float bv = bias ? bias[gc] : 0.f;
#pragma unroll
    for (int mi = 0; mi < 4; ++mi)
#pragma unroll
      for (int r = 0; r < 4; ++r) {
        int gr = m0 + wm + mi * 16 + quad * 4 + r;
        store_out(&C[(size_t)gr * ldc + gc], acc[mi][ni][r] + bv);
      }
  }
}

// -------- q softmax over d, serial per (row, head), no shuffles ------------
__global__ __launch_bounds__(256) void q_softmax_serial(bf16_t* __restrict__ qkv) {
  int gid = blockIdx.x * 256 + threadIdx.x;   // 0 .. 131071
  int row = gid >> 3, h = gid & 7;
  bf16_t* p = qkv + (size_t)row * QKV_LD + h * 64;
  float v[64];
  float m = -1e30f;
#pragma unroll
  for (int i = 0; i < 64; ++i) { v[i] = b2f(p[i]); m = fmaxf(m, v[i]); }
  float s = 0.f;
#pragma unroll
  for (int i = 0; i < 64; ++i) { float e = __expf(v[i] - m); v[i] = e; s += e; }
  float inv = 0.125f / s;
#pragma unroll
  for (int i = 0; i < 64; ++i) p[i] = f2b(v[i] * inv);
}

// ---------------- k column stats (softmax over n), serial ------------------
__global__ __launch_bounds__(512) void k_stats_partial(
    const bf16_t* __restrict__ qkv, float2* __restrict__ part) {
  int c = blockIdx.x, b = blockIdx.y, t = threadIdx.x;
  const bf16_t* p = qkv + (size_t)(b * NN + c * 128) * QKV_LD + HID + t;
  float m = -1e30f, s = 0.f;
  for (int r = 0; r < 128; ++r) {
    float v = b2f(p[(size_t)r * QKV_LD]);
    float nm = fmaxf(m, v);
    s = s * __expf(m - nm) + __expf(v - nm);
    m = nm;
  }
  part[(size_t)(b * 32 + c) * 512 + t] = make_float2(m, s);
}

__global__ __launch_bounds__(512) void k_stats_final(
    const float2* __restrict__ part, float2* __restrict__ fin) {
  int b = blockIdx.x, t = threadIdx.x;
  float m = -1e30f, s = 0.f;
  for (int c = 0; c < 32; ++c) {
    float2 q = part[(size_t)(b * 32 + c) * 512 + t];
    float nm = fmaxf(m, q.x);
    s = s * __expf(m - nm) + q.y * __expf(q.x - nm);
    m = nm;
  }
  fin[b * 512 + t] = make_float2(m, 1.f / s);
}

// ------ context VALU: cPart[p][bh][d][e] = sum_{n in part} ksm[d,n]*v[e,n] -
__global__ __launch_bounds__(256) void context_valu(
    const bf16_t* __restrict__ qkv, const float2* __restrict__ fin,
    float* __restrict__ cPart) {
  int part = blockIdx.x;   // 0..3 (1024 n each)
  int bh = blockIdx.y;     // 0..31
  int b = bh >> 3, h = bh & 7;
  __shared__ float ksh[64][65];   // [n_local][d]
  __shared__ float vsh[64][65];   // [n_local][e]
  __shared__ float2 st[64];
  int t = threadIdx.x;
  if (t < 64) st[t] = fin[b * 512 + h * 64 + t];
  __syncthreads();
  int d = t & 63;
  int eg = (t >> 6) * 16;
  float acc[16];
#pragma unroll
  for (int e = 0; e < 16; ++e) acc[e] = 0.f;
  for (int nt = 0; nt < 16; ++nt) {
    int n0 = part * 1024 + nt * 64;
    __syncthreads();
#pragma unroll
    for (int i = 0; i < 16; ++i) {
      int u = t + i * 256; int nr = u >> 6, c = u & 63;
      const bf16_t* row = qkv + (size_t)(b * NN + n0 + nr) * QKV_LD;
      ksh[nr][c] = __expf(b2f(row[HID + h * 64 + c]) - st[c].x) * st[c].y;
      vsh[nr][c] = b2f(row[2 * HID + h * 64 + c]);
    }
    __syncthreads();
    for (int n = 0; n < 64; ++n) {
      float kv = ksh[n][d];
#pragma unroll
      for (int e = 0; e < 16; ++e) acc[e] += kv * vsh[n][eg + e];
    }
  }
#pragma unroll
  for (int e = 0; e < 16; ++e)
    cPart[((size_t)(part * 32 + bh) * 64 + d) * 64 + eg + e] = acc[e];
}

__global__ __launch_bounds__(256) void ctx_combine(
    const float* __restrict__ cPart, float* __restrict__ ctx) {
  int bh = blockIdx.x, t = threadIdx.x;
#pragma unroll
  for (int i = 0; i < 16; ++i) {
    int idx = t + i * 256;    // d*64 + e
    float s = 0.f;
#pragma unroll
    for (int p = 0; p < 4; ++p) s += cPart[(size_t)(p * 32 + bh) * 4096 + idx];
    ctx[(size_t)bh * 4096 + idx] = s;
  }
}

// ------ attn VALU: attn[n][h*64+e] = sum_d qsm[n][h*64+d] * ctx[bh][d][e] --
__global__ __launch_bounds__(256) void attn_valu(
    const bf16_t* __restrict__ qkv, const float* __restrict__ ctx,
    bf16_t* __restrict__ attn) {
  int nt = blockIdx.x;     // 0..63
  int bh = blockIdx.y;     // 0..31
  int b = bh >> 3, h = bh & 7;
  __shared__ float ctxs[64][65];  // [d][e]
  __shared__ float qs[64][65];    // [d][n_local] (transposed staging)
  int t = threadIdx.x;
#pragma unroll
  for (int i = 0; i < 16; ++i) {
    int u = t + i * 256; int dd = u >> 6, e = u & 63;
    ctxs[dd][e] = ctx[(size_t)bh * 4096 + dd * 64 + e];
  }
#pragma unroll
  for (int i = 0; i < 16; ++i) {
    int u = t + i * 256; int nr = u >> 6, c = u & 63;
    qs[c][nr] = b2f(qkv[(size_t)(b * NN + nt * 64 + nr) * QKV_LD + h * 64 + c]);
  }
  __syncthreads();
  int e = t & 63;
  int ng = (t >> 6) * 16;
  float acc[16];
#pragma unroll
  for (int n = 0; n < 16; ++n) acc[n] = 0.f;
  for (int d = 0; d < 64; ++d) {
    float cv = ctxs[d][e];
#pragma unroll
    for (int n = 0; n < 16; ++n) acc[n] += qs[d][ng + n] * cv;
  }
#pragma unroll
  for (int n = 0; n < 16; ++n)
    attn[(size_t)(b * NN + nt * 64 + ng + n) * HID + h * 64 + e] = f2b(acc[n]);
}

// ---------------- launch ---------------------------------------------------
extern "C" void kernel_launch(void* const* d_in, const int* in_sizes, int n_in,
                              void* d_out, int out_size, void* d_ws, size_t ws_size,
                              hipStream_t stream) {
  const float* x  = (const float*)d_in[0];
  const float* Wq = (const float*)d_in[1];
  const float* Wk = (const float*)d_in[2];
  const float* Wv = (const float*)d_in[3];
  const float* Wo = (const float*)d_in[4];
  const float* bo = (const float*)d_in[5];
  float* out = (float*)d_out;    // fp32 output (hypothesis H1; r2's crash = infra)
  char* ws = (char*)d_ws;

  bf16_t* qkv   = (bf16_t*)(ws + OFF_QKV);
  bf16_t* WTall = (bf16_t*)(ws + OFF_WT);
  bf16_t* WoT   = (bf16_t*)(ws + OFF_WOT);
  float2* statP = (float2*)(ws + OFF_SP);
  float2* statF = (float2*)(ws + OFF_SF);
  float*  cPart = (float*)(ws + OFF_CP);
  float*  ctx   = (float*)(ws + OFF_CTX);
  bf16_t* attn  = (bf16_t*)(ws + OFF_ATT);

  // transpose (+downconvert) weights: W[k][n] -> WT[n][k] bf16
  transpose_tile<<<dim3(8, 16), 256, 0, stream>>>(Wq, WTall, QDIM, HID);
  transpose_tile<<<dim3(8, 16), 256, 0, stream>>>(Wk, WTall + (size_t)HID * QDIM, QDIM, HID);
  transpose_tile<<<dim3(8, 16), 256, 0, stream>>>(Wv, WTall + (size_t)2 * HID * QDIM, QDIM, HID);
  transpose_tile<<<dim3(16, 8), 256, 0, stream>>>(Wo, WoT, HID, QDIM);

  // QKV projection: [16384,1024](f32) @ [1024,1536] -> bf16 qkv
  gemm128<float, bf16_t><<<dim3(12, 128), 256, 0, stream>>>(
      x, QDIM, WTall, QDIM, qkv, QKV_LD, nullptr, QDIM);

  // q softmax (in place, * SCALE), serial per (row, head)
  q_softmax_serial<<<512, 256, 0, stream>>>(qkv);

  // k column softmax stats
  k_stats_partial<<<dim3(32, 4), 512, 0, stream>>>(qkv, statP);
  k_stats_final<<<4, 512, 0, stream>>>(statP, statF);

  // context via VALU directly from qkv layout
  context_valu<<<dim3(4, 32), 256, 0, stream>>>(qkv, statF, cPart);
  ctx_combine<<<32, 256, 0, stream>>>(cPart, ctx);

  // attn out via VALU
  attn_valu<<<dim3(64, 32), 256, 0, stream>>>(qkv, ctx, attn);

  // final projection + bias: [16384,512] @ [512,1024] + bo -> f32 out
  gemm128<bf16_t, float><<<dim3(8, 128), 256, 0, stream>>>(
      attn, HID, WoT, HID, out, QDIM, bo, HID);
}

// Round 7
// 387.777 us; speedup vs baseline: 1.2608x; 1.2608x over previous
//
#include <hip/hip_runtime.h>
#include <hip/hip_bf16.h>

typedef __bf16 bf16_t;
typedef bf16_t bf16x8 __attribute__((ext_vector_type(8)));
typedef float floatx4 __attribute__((ext_vector_type(4)));

#define BB 4
#define NN 4096
#define QDIM 1024
#define HEADS 8
#define DHEAD 64
#define HID 512
#define ROWS (BB*NN)      /* 16384 */
#define QKV_LD 1536

__device__ __forceinline__ float b2f(bf16_t v){ return (float)v; }
__device__ __forceinline__ bf16_t f2b(float v){ return (bf16_t)v; }

__device__ __forceinline__ bf16x8 load8(const bf16_t* p) { return *(const bf16x8*)p; }
__device__ __forceinline__ bf16x8 load8(const float* p) {
  float4 a = *(const float4*)p;
  float4 b = *(const float4*)(p + 4);
  bf16x8 r;
  r[0]=f2b(a.x); r[1]=f2b(a.y); r[2]=f2b(a.z); r[3]=f2b(a.w);
  r[4]=f2b(b.x); r[5]=f2b(b.y); r[6]=f2b(b.z); r[7]=f2b(b.w);
  return r;
}
__device__ __forceinline__ void store_out(bf16_t* p, float v){ *p = f2b(v); }
__device__ __forceinline__ void store_out(float*  p, float v){ *p = v; }

// ---------------- workspace layout (bytes); total ~77.6MB (<114.6MB proven) -
static constexpr size_t OFF_QKV = 0;                      // 16384*1536*2 = 50331648
static constexpr size_t OFF_WT  = 50331648;               // 1536*1024*2  = 3145728
static constexpr size_t OFF_WOT = OFF_WT  + 3145728;      // 1024*512*2   = 1048576
static constexpr size_t OFF_SP  = OFF_WOT + 1048576;      // 4*32*512*8   = 1048576
static constexpr size_t OFF_SF  = OFF_SP  + 1048576;      // 4*512*8      = 16384
static constexpr size_t OFF_CP  = OFF_SF  + 16384;        // 16*32*4096*4 = 8388608
static constexpr size_t OFF_CTX = OFF_CP  + 8388608;      // 32*4096*4    = 524288
static constexpr size_t OFF_ATT = OFF_CTX + 524288;       // 16384*512*2  = 16777216

// ---------------- 64x64 tile transpose: float in -> bf16 out ---------------
__global__ __launch_bounds__(256) void transpose_tile(
    const float* __restrict__ in, bf16_t* __restrict__ out, int R, int C) {
  __shared__ bf16_t T[64][68];
  int r0 = blockIdx.y * 64, c0 = blockIdx.x * 64;
  int t = threadIdx.x;
#pragma unroll
  for (int i = 0; i < 2; ++i) {
    int u = t + i * 256; int rr = u >> 3, c8 = (u & 7) * 8;
    bf16x8 v = load8(&in[(size_t)(r0 + rr) * C + c0 + c8]);
#pragma unroll
    for (int j = 0; j < 8; ++j) T[c8 + j][rr] = v[j];
  }
  __syncthreads();
#pragma unroll
  for (int i = 0; i < 2; ++i) {
    int u = t + i * 256; int cr = u >> 3, r8 = (u & 7) * 8;
    bf16x8 v;
#pragma unroll
    for (int j = 0; j < 8; ++j) v[j] = T[cr][r8 + j];
    *(bf16x8*)&out[(size_t)(c0 + cr) * R + r0 + r8] = v;
  }
}

// ------- 128x128 MFMA GEMM: C[M,N] = A[M,K] @ BT[N,K]^T (+optional bias) ---
// Validated round 6. C/D layout: row=(lane>>4)*4+reg, col=lane&15.
template <typename AT, typename OT>
__global__ __launch_bounds__(256, 2) void gemm128(
    const AT* __restrict__ A, int lda,
    const bf16_t* __restrict__ BT, int ldb,
    OT* __restrict__ C, int ldc,
    const float* __restrict__ bias, int K) {
  __shared__ bf16_t As[128][56];
  __shared__ bf16_t Bs[128][56];
  int m0 = blockIdx.y * 128, n0 = blockIdx.x * 128;
  int t = threadIdx.x;
  int w = t >> 6, lane = t & 63;
  int wm = (w >> 1) * 64, wn = (w & 1) * 64;
  int lr = lane & 15, lk = (lane >> 4) * 8;

  floatx4 acc[4][4];
#pragma unroll
  for (int mi = 0; mi < 4; ++mi)
#pragma unroll
    for (int ni = 0; ni < 4; ++ni) acc[mi][ni] = (floatx4){0.f, 0.f, 0.f, 0.f};

  for (int k0 = 0; k0 < K; k0 += 32) {
#pragma unroll
    for (int i = 0; i < 2; ++i) {
      int u = t + i * 256; int r = u >> 2, c = (u & 3) * 8;
      *(bf16x8*)&As[r][c] = load8(&A[(size_t)(m0 + r) * lda + k0 + c]);
      *(bf16x8*)&Bs[r][c] = load8(&BT[(size_t)(n0 + r) * ldb + k0 + c]);
    }
    __syncthreads();
    bf16x8 af[4], bfr[4];
#pragma unroll
    for (int mi = 0; mi < 4; ++mi) af[mi] = *(const bf16x8*)&As[wm + mi * 16 + lr][lk];
#pragma unroll
    for (int ni = 0; ni < 4; ++ni) bfr[ni] = *(const bf16x8*)&Bs[wn + ni * 16 + lr][lk];
#pragma unroll
    for (int mi = 0; mi < 4; ++mi)
#pragma unroll
      for (int ni = 0; ni < 4; ++ni)
        acc[mi][ni] = __builtin_amdgcn_mfma_f32_16x16x32_bf16(af[mi], bfr[ni], acc[mi][ni], 0, 0, 0);
    __syncthreads();
  }
  int quad = (lane >> 4);
#pragma unroll
  for (int ni = 0; ni < 4; ++ni) {
    int gc = n0 + wn + ni * 16 + lr;
    float bv = bias ? bias[gc] : 0.f;
#pragma unroll
    for (int mi = 0; mi < 4; ++mi)
#pragma unroll
      for (int r = 0; r < 4; ++r) {
        int gr = m0 + wm + mi * 16 + quad * 4 + r;
        store_out(&C[(size_t)gr * ldc + gc], acc[mi][ni][r] + bv);
      }
  }
}

// -------- q softmax over d, serial per (row, head), no shuffles ------------
__global__ __launch_bounds__(256) void q_softmax_serial(bf16_t* __restrict__ qkv) {
  int gid = blockIdx.x * 256 + threadIdx.x;   // 0 .. 131071
  int row = gid >> 3, h = gid & 7;
  bf16_t* p = qkv + (size_t)row * QKV_LD + h * 64;
  float v[64];
  float m = -1e30f;
#pragma unroll
  for (int i = 0; i < 64; ++i) { v[i] = b2f(p[i]); m = fmaxf(m, v[i]); }
  float s = 0.f;
#pragma unroll
  for (int i = 0; i < 64; ++i) { float e = __expf(v[i] - m); v[i] = e; s += e; }
  float inv = 0.125f / s;
#pragma unroll
  for (int i = 0; i < 64; ++i) p[i] = f2b(v[i] * inv);
}

// ---------------- k column stats (softmax over n), serial ------------------
__global__ __launch_bounds__(512) void k_stats_partial(
    const bf16_t* __restrict__ qkv, float2* __restrict__ part) {
  int c = blockIdx.x, b = blockIdx.y, t = threadIdx.x;
  const bf16_t* p = qkv + (size_t)(b * NN + c * 128) * QKV_LD + HID + t;
  float m = -1e30f, s = 0.f;
  for (int r = 0; r < 128; ++r) {
    float v = b2f(p[(size_t)r * QKV_LD]);
    float nm = fmaxf(m, v);
    s = s * __expf(m - nm) + __expf(v - nm);
    m = nm;
  }
  part[(size_t)(b * 32 + c) * 512 + t] = make_float2(m, s);
}

__global__ __launch_bounds__(512) void k_stats_final(
    const float2* __restrict__ part, float2* __restrict__ fin) {
  int b = blockIdx.x, t = threadIdx.x;
  float m = -1e30f, s = 0.f;
  for (int c = 0; c < 32; ++c) {
    float2 q = part[(size_t)(b * 32 + c) * 512 + t];
    float nm = fmaxf(m, q.x);
    s = s * __expf(m - nm) + q.y * __expf(q.x - nm);
    m = nm;
  }
  fin[b * 512 + t] = make_float2(m, 1.f / s);
}

// ------ context MFMA: cPart[chunk][bh][d][e] = sum_{n in chunk} ksm[d,n]*v[e,n]
// Mirrors gemm128's validated fragment reads/epilogue; 256-n chunk per block.
__global__ __launch_bounds__(256) void context_mfma(
    const bf16_t* __restrict__ qkv, const float2* __restrict__ fin,
    float* __restrict__ cPart) {
  int chunk = blockIdx.x;  // 0..15 (256 n each)
  int bh = blockIdx.y;     // 0..31
  int b = bh >> 3, h = bh & 7;
  __shared__ bf16_t ksh[64][72];   // [d][n_local], row stride 144B (16B-mult)
  __shared__ bf16_t vsh[64][72];   // [e][n_local]
  __shared__ float2 st[64];
  int t = threadIdx.x;
  if (t < 64) st[t] = fin[b * 512 + h * 64 + t];
  int w = t >> 6, lane = t & 63;
  int lr = lane & 15, lk = (lane >> 4) * 8;
  floatx4 acc[4];
#pragma unroll
  for (int ni = 0; ni < 4; ++ni) acc[ni] = (floatx4){0.f, 0.f, 0.f, 0.f};

  for (int nt = 0; nt < 4; ++nt) {
    int n0 = chunk * 256 + nt * 64;
    __syncthreads();
    // stage 64n x 64d of k (exp-normalized) and v, transposed to [d][n]
#pragma unroll
    for (int i = 0; i < 2; ++i) {
      int u = t + i * 256; int nr = u >> 3, d8 = (u & 7) * 8;
      const bf16_t* base = qkv + (size_t)(b * NN + n0 + nr) * QKV_LD + h * 64 + d8;
      bf16x8 kv = *(const bf16x8*)(base + HID);
      bf16x8 vv = *(const bf16x8*)(base + 2 * HID);
#pragma unroll
      for (int j = 0; j < 8; ++j) {
        int d = d8 + j;
        ksh[d][nr] = f2b(__expf(b2f(kv[j]) - st[d].x) * st[d].y);
        vsh[d][nr] = vv[j];
      }
    }
    __syncthreads();
#pragma unroll
    for (int s = 0; s < 2; ++s) {
      bf16x8 a = *(const bf16x8*)&ksh[w * 16 + lr][s * 32 + lk];
#pragma unroll
      for (int ni = 0; ni < 4; ++ni) {
        bf16x8 bb = *(const bf16x8*)&vsh[ni * 16 + lr][s * 32 + lk];
        acc[ni] = __builtin_amdgcn_mfma_f32_16x16x32_bf16(a, bb, acc[ni], 0, 0, 0);
      }
    }
  }
  // epilogue (m89 layout): d = w*16 + quad*4 + r, e = ni*16 + lr
  float* op = cPart + (size_t)(chunk * 32 + bh) * 4096;
  int quad = lane >> 4;
#pragma unroll
  for (int ni = 0; ni < 4; ++ni)
#pragma unroll
    for (int r = 0; r < 4; ++r)
      op[(w * 16 + quad * 4 + r) * 64 + ni * 16 + lr] = acc[ni][r];
}

__global__ __launch_bounds__(256) void ctx_combine(
    const float* __restrict__ cPart, float* __restrict__ ctx) {
  int bh = blockIdx.x, t = threadIdx.x;
#pragma unroll
  for (int i = 0; i < 16; ++i) {
    int idx = t + i * 256;    // d*64 + e
    float s = 0.f;
#pragma unroll
    for (int p = 0; p < 16; ++p) s += cPart[(size_t)(p * 32 + bh) * 4096 + idx];
    ctx[(size_t)bh * 4096 + idx] = s;
  }
}

// ------ attn VALU: attn[n][h*64+e] = sum_d qsm[n][h*64+d] * ctx[bh][d][e] --
__global__ __launch_bounds__(256) void attn_valu(
    const bf16_t* __restrict__ qkv, const float* __restrict__ ctx,
    bf16_t* __restrict__ attn) {
  int nt = blockIdx.x;     // 0..63
  int bh = blockIdx.y;     // 0..31
  int b = bh >> 3, h = bh & 7;
  __shared__ float ctxs[64][65];  // [d][e]
  __shared__ float qs[64][65];    // [d][n_local] (transposed staging)
  int t = threadIdx.x;
#pragma unroll
  for (int i = 0; i < 16; ++i) {
    int u = t + i * 256; int dd = u >> 6, e = u & 63;
    ctxs[dd][e] = ctx[(size_t)bh * 4096 + dd * 64 + e];
  }
#pragma unroll
  for (int i = 0; i < 16; ++i) {
    int u = t + i * 256; int nr = u >> 6, c = u & 63;
    qs[c][nr] = b2f(qkv[(size_t)(b * NN + nt * 64 + nr) * QKV_LD + h * 64 + c]);
  }
  __syncthreads();
  int e = t & 63;
  int ng = (t >> 6) * 16;
  float acc[16];
#pragma unroll
  for (int n = 0; n < 16; ++n) acc[n] = 0.f;
  for (int d = 0; d < 64; ++d) {
    float cv = ctxs[d][e];
#pragma unroll
    for (int n = 0; n < 16; ++n) acc[n] += qs[d][ng + n] * cv;
  }
#pragma unroll
  for (int n = 0; n < 16; ++n)
    attn[(size_t)(b * NN + nt * 64 + ng + n) * HID + h * 64 + e] = f2b(acc[n]);
}

// ---------------- launch ---------------------------------------------------
extern "C" void kernel_launch(void* const* d_in, const int* in_sizes, int n_in,
                              void* d_out, int out_size, void* d_ws, size_t ws_size,
                              hipStream_t stream) {
  const float* x  = (const float*)d_in[0];
  const float* Wq = (const float*)d_in[1];
  const float* Wk = (const float*)d_in[2];
  const float* Wv = (const float*)d_in[3];
  const float* Wo = (const float*)d_in[4];
  const float* bo = (const float*)d_in[5];
  float* out = (float*)d_out;
  char* ws = (char*)d_ws;

  bf16_t* qkv   = (bf16_t*)(ws + OFF_QKV);
  bf16_t* WTall = (bf16_t*)(ws + OFF_WT);
  bf16_t* WoT   = (bf16_t*)(ws + OFF_WOT);
  float2* statP = (float2*)(ws + OFF_SP);
  float2* statF = (float2*)(ws + OFF_SF);
  float*  cPart = (float*)(ws + OFF_CP);
  float*  ctx   = (float*)(ws + OFF_CTX);
  bf16_t* attn  = (bf16_t*)(ws + OFF_ATT);

  // transpose (+downconvert) weights: W[k][n] -> WT[n][k] bf16
  transpose_tile<<<dim3(8, 16), 256, 0, stream>>>(Wq, WTall, QDIM, HID);
  transpose_tile<<<dim3(8, 16), 256, 0, stream>>>(Wk, WTall + (size_t)HID * QDIM, QDIM, HID);
  transpose_tile<<<dim3(8, 16), 256, 0, stream>>>(Wv, WTall + (size_t)2 * HID * QDIM, QDIM, HID);
  transpose_tile<<<dim3(16, 8), 256, 0, stream>>>(Wo, WoT, HID, QDIM);

  // QKV projection: [16384,1024](f32) @ [1024,1536] -> bf16 qkv
  gemm128<float, bf16_t><<<dim3(12, 128), 256, 0, stream>>>(
      x, QDIM, WTall, QDIM, qkv, QKV_LD, nullptr, QDIM);

  // q softmax (in place, * SCALE), serial per (row, head)
  q_softmax_serial<<<512, 256, 0, stream>>>(qkv);

  // k column softmax stats
  k_stats_partial<<<dim3(32, 4), 512, 0, stream>>>(qkv, statP);
  k_stats_final<<<4, 512, 0, stream>>>(statP, statF);

  // context via MFMA (fused exp-normalize + transpose staging in LDS)
  context_mfma<<<dim3(16, 32), 256, 0, stream>>>(qkv, statF, cPart);
  ctx_combine<<<32, 256, 0, stream>>>(cPart, ctx);

  // attn out via VALU
  attn_valu<<<dim3(64, 32), 256, 0, stream>>>(qkv, ctx, attn);

  // final projection + bias: [16384,512] @ [512,1024] + bo -> f32 out
  gemm128<bf16_t, float><<<dim3(8, 128), 256, 0, stream>>>(
      attn, HID, WoT, HID, out, QDIM, bo, HID);
}